// Round 12
// baseline (475.946 us; speedup 1.0000x reference)
//
#include <hip/hip_runtime.h>
#include <hip/hip_bf16.h>

#define N_NODES 20000
#define E_EDGES 320000
#define E_TOT   (E_EDGES + N_NODES)
#define IN_CH   128
#define HID     256
#define HEADS   8
#define CPH     32

enum { EP_BIAS = 0, EP_BN_LRELU = 1, EP_LRELU = 2 };

typedef _Float16 f16;
typedef f16  f16x2 __attribute__((ext_vector_type(2)));
typedef f16  f16x4 __attribute__((ext_vector_type(4)));
typedef f16  f16x8 __attribute__((ext_vector_type(8)));
typedef float f32x2 __attribute__((ext_vector_type(2)));
typedef float f32x4 __attribute__((ext_vector_type(4)));

__device__ __forceinline__ f16x2 h2max(f16x2 a, f16x2 b) {
#if __has_builtin(__builtin_elementwise_max)
    return __builtin_elementwise_max(a, b);
#else
    f16x2 r; r[0] = a[0] > b[0] ? a[0] : b[0]; r[1] = a[1] > b[1] ? a[1] : b[1]; return r;
#endif
}
__device__ __forceinline__ float hdot2(f16x2 a, f16x2 b, float c) {
#if __has_builtin(__builtin_amdgcn_fdot2)
    return __builtin_amdgcn_fdot2(a, b, c, false);
#else
    return c + (float)a[0] * (float)b[0] + (float)a[1] * (float)b[1];
#endif
}
__device__ __forceinline__ float fexp2(float x) {
#if __has_builtin(__builtin_amdgcn_exp2f)
    return __builtin_amdgcn_exp2f(x);
#else
    return exp2f(x);
#endif
}

// Fragment-major activation layout [rb][kb][ks][lane][8]: element (row, col):
//   rb=row>>4, m=row&15, kb=col>>6, ks=(col>>5)&1, q=(col>>3)&3, e=col&7, lane=(q<<4)|m
__device__ __forceinline__ size_t frag_idx(int row, int col, int KB) {
    int kb = col >> 6, ks = (col >> 5) & 1, q = (col >> 3) & 3, e = col & 7;
    return ((((size_t)(row >> 4) * KB + kb) * 2 + ks) << 9) + (((q << 4) | (row & 15)) << 3) + e;
}

// ---------------- weight prep: fp32 [K,Nc] -> fp16 fragment-major (B-operand) ----------------
struct WDesc { const float* src; f16* dst; int K; int Nc; int NTOT; int ct0; };
struct WDescs { WDesc d[14]; };

__global__ __launch_bounds__(256)
void wprep_kernel(WDescs ds) {
    WDesc w = ds.d[blockIdx.y];
    int total = w.K * w.Nc;
    int i = blockIdx.x * 256 + threadIdx.x;
    if (i < total) {
        int NT_local = w.Nc >> 4;
        int e  = i & 7;
        int l  = (i >> 3) & 63;
        int r  = i >> 9;
        int ct = r % NT_local;
        int q  = r / NT_local;
        int ks = q & 1;
        int kb = q >> 1;
        int n  = ct * 16 + (l & 15);
        int k  = kb * 64 + ks * 32 + ((l >> 4) << 3) + e;
        size_t di = (((size_t)(kb * 2 + ks) * w.NTOT + w.ct0 + ct) << 9) + (l << 3) + e;
        w.dst[di] = (f16)w.src[(size_t)k * w.Nc + n];
    }
}

// x fp32 row-major [N,128] -> f16 fragment-major (KB=2)
__global__ void cvt_frag_kernel(const float* __restrict__ in, f16* __restrict__ out) {
    int i = blockIdx.x * 256 + threadIdx.x;
    if (i < N_NODES * IN_CH) {
        int row = i / IN_CH, col = i - row * IN_CH;
        out[frag_idx(row, col, 2)] = (f16)in[i];
    }
}

// ---------------- barrier-free fp16 MFMA GEMM, frag-major A ----------------
template<int NT, int NTOT, int WAVES, int RT, int DOT, int OUTF>
__global__ __launch_bounds__(WAVES * 64)
void gemm_kernel(const f16* __restrict__ A1, int KB1,
                 const f16* __restrict__ A2, int KB2,
                 const f16* __restrict__ Wf,
                 const float* __restrict__ biasA,
                 const float* __restrict__ biasB,
                 const float* __restrict__ bng,
                 const float* __restrict__ bnb,
                 f16* __restrict__ out16A,
                 f16* __restrict__ out16B,
                 f16* __restrict__ dup16,
                 float* __restrict__ out32,
                 const float* __restrict__ dotw,
                 const float* __restrict__ dotb,
                 float* __restrict__ outdot,
                 int NcA, int KBo, int mode)
{
    __shared__ float red[DOT ? 16 : 1][DOT ? 65 : 1];
    const int tid  = threadIdx.x;
    const int wave = tid >> 6;
    const int lane = tid & 63;
    const int quad = lane >> 4;
    const int rb0 = blockIdx.x * RT;
    const int KBt = KB1 + KB2;

    f32x4 acc[RT][NT];
#pragma unroll
    for (int t = 0; t < RT; ++t)
#pragma unroll
        for (int j = 0; j < NT; ++j) acc[t][j] = (f32x4){0.f, 0.f, 0.f, 0.f};

#pragma unroll 2
    for (int kb = 0; kb < KBt; ++kb) {
#pragma unroll
        for (int ks = 0; ks < 2; ++ks) {
            f16x8 a[RT];
#pragma unroll
            for (int t = 0; t < RT; ++t) {
                const f16* ap = (kb < KB1)
                    ? A1 + (((((size_t)(rb0 + t)) * KB1 + kb) * 2 + ks) << 9) + (lane << 3)
                    : A2 + (((((size_t)(rb0 + t)) * KB2 + (kb - KB1)) * 2 + ks) << 9) + (lane << 3);
                a[t] = *(const f16x8*)ap;      // 64 x 16 B contiguous: one coalesced load
            }
            const f16* bp = Wf + (((size_t)(kb * 2 + ks) * NTOT + wave * NT) << 9) + (lane << 3);
#pragma unroll
            for (int ct = 0; ct < NT; ++ct) {
                f16x8 b = *(const f16x8*)(bp + ((size_t)ct << 9));
#pragma unroll
                for (int t = 0; t < RT; ++t)
                    acc[t][ct] = __builtin_amdgcn_mfma_f32_16x16x32_f16(a[t], b, acc[t][ct], 0, 0, 0);
            }
        }
    }

    // epilogue: C/D layout col=lane&15, row=quad*4+reg
    const int c0 = lane & 15;
    const int NcB = NTOT * 16 - NcA;
#pragma unroll
    for (int t = 0; t < RT; ++t) {
        const int r0 = (rb0 + t) * 16 + (quad << 2);
#pragma unroll
        for (int ct = 0; ct < NT; ++ct) {
            int col = (wave * NT + ct) * 16 + c0;
            bool isB = col >= NcA;
            int colL = isB ? col - NcA : col;
            float bv = isB ? biasB[colL] : biasA[colL];
            float sc = 1.f, sh = 0.f;
            if (mode == EP_BN_LRELU) {
                sc = bng[col] * rsqrtf(1.f + 1e-5f);
                sh = bnb[col];
            }
#pragma unroll
            for (int reg = 0; reg < 4; ++reg) {
                int row = r0 + reg;
                float v = acc[t][ct][reg] + bv;
                if (mode == EP_BN_LRELU) { v = v * sc + sh; v = v > 0.f ? v : 0.1f * v; }
                else if (mode == EP_LRELU) { v = v > 0.f ? v : 0.1f * v; }
                if (DOT) {
                    red[(quad << 2) + reg][col] = v * dotw[col];
                } else if (OUTF) {
                    size_t idx = frag_idx(row, col, KBo);
                    out16A[idx] = (f16)v;
                    if (dup16) dup16[idx] = (f16)v;
                    if (out32) out32[(size_t)row * NcA + col] = v;
                } else {
                    f16* Cout = isB ? out16B : out16A;
                    int stride = isB ? NcB : NcA;
                    Cout[(size_t)row * stride + colL] = (f16)v;
                }
            }
        }
    }

    if (DOT) {   // RT==1, NTOT*16 == 64
        __syncthreads();
        if (wave == 0) {
            int r = lane & 15, q = lane >> 4;
            float psum = 0.f;
#pragma unroll
            for (int j = 0; j < 16; ++j) psum += red[r][q * 16 + j];
            psum += __shfl_xor(psum, 16, 64);
            psum += __shfl_xor(psum, 32, 64);
            if (lane < 16) outdot[rb0 * 16 + r] = psum + dotb[0];
        }
    }
}

// ---------------- CSR build ----------------
__global__ void deg_count_kernel(const int* __restrict__ dst, int* __restrict__ cnt) {
    int e = blockIdx.x * 256 + threadIdx.x;
    if (e < E_EDGES) atomicAdd(&cnt[dst[e]], 1);
}
__global__ __launch_bounds__(1024)
void scan_kernel(const int* __restrict__ cnt, int* __restrict__ off) {
    __shared__ int wsum[16];
    __shared__ int wpre[16];
    __shared__ int tot_s;
    __shared__ int carry_s;
    const int tid = threadIdx.x, wv = tid >> 6, ln = tid & 63;
    if (tid == 0) carry_s = 0;
    __syncthreads();
    for (int base = 0; base < N_NODES; base += 1024) {
        int i = base + tid;
        int v = (i < N_NODES) ? cnt[i] + 1 : 0;   // +1 = self loop
        int s = v;
#pragma unroll
        for (int d = 1; d < 64; d <<= 1) { int t = __shfl_up(s, d, 64); if (ln >= d) s += t; }
        if (ln == 63) wsum[wv] = s;
        __syncthreads();
        if (tid < 16) {
            int t = wsum[tid];
            int sc = t;
#pragma unroll
            for (int d = 1; d < 16; d <<= 1) { int u = __shfl_up(sc, d, 16); if (tid >= d) sc += u; }
            wpre[tid] = sc - t;
            if (tid == 15) tot_s = sc;
        }
        __syncthreads();
        if (i < N_NODES) off[i] = carry_s + wpre[wv] + s - v;
        __syncthreads();
        if (tid == 0) carry_s += tot_s;
        __syncthreads();
    }
    if (threadIdx.x == 0) off[N_NODES] = carry_s;
}
__global__ void fill_kernel(const int* __restrict__ src, const int* __restrict__ dst,
                            const int* __restrict__ off, int* __restrict__ cur, int* __restrict__ csr) {
    int i = blockIdx.x * 256 + threadIdx.x;
    if (i < E_EDGES) {
        int d = dst[i];
        int pos = atomicAdd(&cur[d], 1);
        csr[off[d] + pos] = src[i];
    } else {
        int j = i - E_EDGES;
        if (j < N_NODES) csr[off[j + 1] - 1] = j;
    }
}

// ---------------- fused GATv2 aggregation: 2 waves/node, 4 ch/thread ----------------
// Block = 256 thr = 4 waves = 2 nodes. Each wave processes half the node's edge list;
// partial (s, o) merged via LDS; half-0 wave finishes softmax+LN+residual.
__global__ __launch_bounds__(256)
void gat_agg_kernel(const f16* __restrict__ xl, const f16* __restrict__ xr,
                    float* __restrict__ g, f16* __restrict__ g16,
                    const int* __restrict__ off, const int* __restrict__ csr,
                    const float* __restrict__ att,
                    const float* __restrict__ bias,
                    const float* __restrict__ lng,
                    const float* __restrict__ lnb)
{
    __shared__ float4 o_l[2][64];
    __shared__ float  s_l[2][8];
    const int wv   = threadIdx.x >> 6;
    const int ln   = threadIdx.x & 63;         // channels 4ln..4ln+3; head = ln>>3
    const int slot = wv >> 1;                  // node within block
    const int half = wv & 1;                   // edge-list half
    const int n    = blockIdx.x * 2 + slot;    // grid = N/2 exact

    const f16x4* xl4 = (const f16x4*)xl;
    f16x4 xrv = ((const f16x4*)xr)[(size_t)n * 64 + ln];
    f16x2 xr01; xr01[0] = xrv[0]; xr01[1] = xrv[1];
    f16x2 xr23; xr23[0] = xrv[2]; xr23[1] = xrv[3];
    float4 avf = ((const float4*)att)[ln];
    const float L2E = 1.44269504f;             // exp(x) = exp2(x*log2e)
    f16x2 av01; av01[0] = (f16)(avf.x * L2E); av01[1] = (f16)(avf.y * L2E);
    f16x2 av23; av23[0] = (f16)(avf.z * L2E); av23[1] = (f16)(avf.w * L2E);
    const f16x2 k02 = { (f16)0.2f, (f16)0.2f };

    float s = 0.f;
    f32x2 o01 = {0.f, 0.f}, o23 = {0.f, 0.f};

    auto proc = [&](f16x4 xv) {
        f16x2 x01; x01[0] = xv[0]; x01[1] = xv[1];
        f16x2 x23; x23[0] = xv[2]; x23[1] = xv[3];
        f16x2 v01 = x01 + xr01;
        f16x2 v23 = x23 + xr23;
        f16x2 l01 = h2max(v01, v01 * k02);     // leaky 0.2 (packed)
        f16x2 l23 = h2max(v23, v23 * k02);
        float pr = hdot2(l01, av01, hdot2(l23, av23, 0.f));
        pr += __shfl_xor(pr, 4, 8);
        pr += __shfl_xor(pr, 2, 8);
        pr += __shfl_xor(pr, 1, 8);            // per-head logit (8 lanes = 32 ch)
        float e = fexp2(pr);                    // logits bounded: no running max needed
        s += e;
        f32x2 xf01 = { (float)xv[0], (float)xv[1] };
        f32x2 xf23 = { (float)xv[2], (float)xv[3] };
        o01 += e * xf01;
        o23 += e * xf23;
    };

    int beg = off[n], end = off[n + 1];
    int lenA = (end - beg + 1) >> 1;
    int p  = half ? beg + lenA : beg;
    int pe = half ? end : beg + lenA;
    for (; p + 4 <= pe; p += 4) {
        int s0 = csr[p], s1 = csr[p + 1], s2 = csr[p + 2], s3 = csr[p + 3];
        f16x4 r0 = xl4[(size_t)s0 * 64 + ln];
        f16x4 r1 = xl4[(size_t)s1 * 64 + ln];
        f16x4 r2 = xl4[(size_t)s2 * 64 + ln];
        f16x4 r3 = xl4[(size_t)s3 * 64 + ln];
        proc(r0); proc(r1); proc(r2); proc(r3);
    }
    for (; p < pe; ++p) {
        f16x4 r0 = xl4[(size_t)csr[p] * 64 + ln];
        proc(r0);
    }

    if (half) {
        if ((ln & 7) == 0) s_l[slot][ln >> 3] = s;
        o_l[slot][ln] = make_float4(o01[0], o01[1], o23[0], o23[1]);
    }
    __syncthreads();
    if (half) return;
    s += s_l[slot][ln >> 3];
    float4 op = o_l[slot][ln];
    o01[0] += op.x; o01[1] += op.y; o23[0] += op.z; o23[1] += op.w;

    float inv = 1.f / (s + 1e-16f);
    float4 bi = ((const float4*)bias)[ln];
    float y0 = o01[0] * inv + bi.x;
    float y1 = o01[1] * inv + bi.y;
    float y2 = o23[0] * inv + bi.z;
    float y3 = o23[1] * inv + bi.w;

    // LayerNorm over 256 channels, pure wave-shuffle
    float s1 = y0 + y1 + y2 + y3;
    float s2 = y0 * y0 + y1 * y1 + y2 * y2 + y3 * y3;
#pragma unroll
    for (int d = 32; d; d >>= 1) { s1 += __shfl_xor(s1, d, 64); s2 += __shfl_xor(s2, d, 64); }
    float mu  = s1 * (1.f / HID);
    float ex2 = s2 * (1.f / HID);
    float rstd = rsqrtf(ex2 - mu * mu + 1e-5f);
    float4 lg = ((const float4*)lng)[ln];
    float4 lb = ((const float4*)lnb)[ln];
    float nv0 = (y0 - mu) * rstd * lg.x + lb.x; nv0 = nv0 > 0.f ? nv0 : 0.1f * nv0;
    float nv1 = (y1 - mu) * rstd * lg.y + lb.y; nv1 = nv1 > 0.f ? nv1 : 0.1f * nv1;
    float nv2 = (y2 - mu) * rstd * lg.z + lb.z; nv2 = nv2 > 0.f ? nv2 : 0.1f * nv2;
    float nv3 = (y3 - mu) * rstd * lg.w + lb.w; nv3 = nv3 > 0.f ? nv3 : 0.1f * nv3;

    float4 gv = ((const float4*)g)[(size_t)n * 64 + ln];
    float g0 = nv0 + gv.x, g1 = nv1 + gv.y, g2 = nv2 + gv.z, g3 = nv3 + gv.w;
    ((float4*)g)[(size_t)n * 64 + ln] = make_float4(g0, g1, g2, g3);
    // g16 mirror in fragment-major layout (KB=4); channels 4ln..4ln+3 share one chunk
    f16x4 gh; gh[0] = (f16)g0; gh[1] = (f16)g1; gh[2] = (f16)g2; gh[3] = (f16)g3;
    *(f16x4*)&g16[frag_idx(n, 4 * ln, 4)] = gh;
}

static inline size_t align_up(size_t v, size_t a) { return (v + a - 1) & ~(a - 1); }

extern "C" void kernel_launch(void* const* d_in, const int* in_sizes, int n_in,
                              void* d_out, int out_size, void* d_ws, size_t ws_size,
                              hipStream_t stream)
{
    const float* x      = (const float*)d_in[0];
    const int*   ei     = (const int*)d_in[1];
    const float* mlp_w1 = (const float*)d_in[2];
    const float* mlp_b1 = (const float*)d_in[3];
    const float* bn1_g  = (const float*)d_in[4];
    const float* bn1_b  = (const float*)d_in[5];
    const float* mlp_w2 = (const float*)d_in[6];
    const float* mlp_b2 = (const float*)d_in[7];
    const float* bn2_g  = (const float*)d_in[8];
    const float* bn2_b  = (const float*)d_in[9];
    const float* mlp_w3 = (const float*)d_in[10];
    const float* mlp_b3 = (const float*)d_in[11];
    const float* gat_wl = (const float*)d_in[12];
    const float* gat_bl = (const float*)d_in[13];
    const float* gat_wr = (const float*)d_in[14];
    const float* gat_br = (const float*)d_in[15];
    const float* gat_att  = (const float*)d_in[16];
    const float* gat_bias = (const float*)d_in[17];
    const float* ln_g   = (const float*)d_in[18];
    const float* ln_b   = (const float*)d_in[19];
    const float* head_w1 = (const float*)d_in[20];
    const float* head_b1 = (const float*)d_in[21];
    const float* hbn1_g  = (const float*)d_in[22];
    const float* hbn1_b  = (const float*)d_in[23];
    const float* head_w2 = (const float*)d_in[24];
    const float* head_b2 = (const float*)d_in[25];
    const float* hbn2_g  = (const float*)d_in[26];
    const float* hbn2_b  = (const float*)d_in[27];
    const float* head_w3 = (const float*)d_in[28];
    const float* head_b3 = (const float*)d_in[29];
    const float* head_w4 = (const float*)d_in[30];
    const float* head_b4 = (const float*)d_in[31];
    float* out = (float*)d_out;

    // ---- workspace layout ----
    char* w = (char*)d_ws;
    size_t p = 0;
    int* off  = (int*)(w + p); p = align_up(p + (N_NODES + 1) * sizeof(int), 64);
    int* fill = (int*)(w + p); p = align_up(p + N_NODES * sizeof(int), 64);
    int* cur  = (int*)(w + p); p = align_up(p + N_NODES * sizeof(int), 64);
    int* csr  = (int*)(w + p); p = align_up(p + E_TOT * sizeof(int), 64);
    float* g32 = (float*)(w + p); p = align_up(p + (size_t)N_NODES * HID * 4, 64);
    auto halloc = [&](size_t elems) {
        f16* q = (f16*)(w + p);
        p = align_up(p + elems * 2, 1024);
        return q;
    };
    f16* x16     = halloc((size_t)N_NODES * IN_CH);   // frag KB=2
    f16* h1      = halloc((size_t)N_NODES * HID);     // frag KB=4
    f16* h2      = halloc((size_t)N_NODES * HID);     // frag KB=4 / KB=2 for head2
    f16* x_mlp16 = halloc((size_t)N_NODES * HID);     // frag KB=4
    f16* g16     = halloc((size_t)N_NODES * HID);     // frag KB=4
    f16* xl16    = halloc((size_t)N_NODES * HID);     // row-major (agg input)
    f16* xr16    = halloc((size_t)N_NODES * HID);     // row-major (agg input)
    f16* wt_mlp1 = halloc((size_t)IN_CH * HID);
    f16* wt_mlp2 = halloc((size_t)HID * HID);
    f16* wt_mlp3 = halloc((size_t)HID * HID);
    f16* wt_g[4];
    for (int i = 0; i < 4; ++i) wt_g[i] = halloc((size_t)HID * 2 * HID);
    f16* wt_h1 = halloc((size_t)2 * HID * HID);
    f16* wt_h2 = halloc((size_t)HID * (HID / 2));
    f16* wt_h3 = halloc((size_t)(HID / 2) * (HID / 4));
    (void)ws_size; (void)in_sizes; (void)n_in; (void)out_size;

    const int* e_src = ei;
    const int* e_dst = ei + E_EDGES;

    dim3 blk(256);
    dim3 gM625((N_NODES + 31) / 32);   // RT=2: 625 exact
    dim3 gM1250((N_NODES + 15) / 16);  // RT=1: 1250 exact

    // ---- weight prep (fp32 -> fp16 fragment-major; wl+wr fused per layer) ----
    WDescs ds;
    ds.d[0]  = { mlp_w1, wt_mlp1, IN_CH, HID, 16, 0 };
    ds.d[1]  = { mlp_w2, wt_mlp2, HID, HID, 16, 0 };
    ds.d[2]  = { mlp_w3, wt_mlp3, HID, HID, 16, 0 };
    for (int i = 0; i < 4; ++i) {
        ds.d[3 + 2 * i] = { gat_wl + (size_t)i * HID * HID, wt_g[i], HID, HID, 32, 0 };
        ds.d[4 + 2 * i] = { gat_wr + (size_t)i * HID * HID, wt_g[i], HID, HID, 32, 16 };
    }
    ds.d[11] = { head_w1, wt_h1, 2 * HID, HID, 16, 0 };
    ds.d[12] = { head_w2, wt_h2, HID, HID / 2, 8, 0 };
    ds.d[13] = { head_w3, wt_h3, HID / 2, HID / 4, 4, 0 };
    {
        dim3 gp((2 * HID * HID + 255) / 256, 14);
        wprep_kernel<<<gp, blk, 0, stream>>>(ds);
    }
    cvt_frag_kernel<<<(N_NODES * IN_CH + 255) / 256, blk, 0, stream>>>(x, x16);

    // ---- CSR by destination ----
    hipMemsetAsync(fill, 0, (size_t)((char*)cur - (char*)fill) + N_NODES * sizeof(int), stream);
    deg_count_kernel<<<(E_EDGES + 255) / 256, blk, 0, stream>>>(e_dst, fill);
    scan_kernel<<<1, 1024, 0, stream>>>(fill, off);
    fill_kernel<<<(E_TOT + 255) / 256, blk, 0, stream>>>(e_src, e_dst, off, cur, csr);

    // ---- MLP stem (frag-major f16 I/O; MLP3 also emits g16 frag + g32 row-major) ----
    gemm_kernel<2, 16, 8, 2, 0, 1><<<gM625, 512, 0, stream>>>(x16, 2, nullptr, 0, wt_mlp1, mlp_b1, mlp_b1,
        bn1_g, bn1_b, h1, nullptr, nullptr, nullptr, nullptr, nullptr, nullptr, HID, 4, EP_BN_LRELU);
    gemm_kernel<2, 16, 8, 2, 0, 1><<<gM625, 512, 0, stream>>>(h1, 4, nullptr, 0, wt_mlp2, mlp_b2, mlp_b2,
        bn2_g, bn2_b, h2, nullptr, nullptr, nullptr, nullptr, nullptr, nullptr, HID, 4, EP_BN_LRELU);
    gemm_kernel<2, 16, 8, 2, 0, 1><<<gM625, 512, 0, stream>>>(h2, 4, nullptr, 0, wt_mlp3, mlp_b3, mlp_b3,
        nullptr, nullptr, x_mlp16, nullptr, g16, g32, nullptr, nullptr, nullptr, HID, 4, EP_BIAS);

    // ---- GAT layers (fused wl|wr dual-output GEMM + fused aggregation) ----
    for (int i = 0; i < 4; ++i) {
        gemm_kernel<4, 32, 8, 2, 0, 0><<<gM625, 512, 0, stream>>>(g16, 4, nullptr, 0, wt_g[i],
            gat_bl + i * HID, gat_br + i * HID, nullptr, nullptr,
            xl16, xr16, nullptr, nullptr, nullptr, nullptr, nullptr, HID, 0, EP_BIAS);
        gat_agg_kernel<<<N_NODES / 2, blk, 0, stream>>>(xl16, xr16, g32, g16, off, csr,
                                                        gat_att + i * HID, gat_bias + i * HID,
                                                        ln_g + i * HID, ln_b + i * HID);
    }

    // ---- regression head (head3 GEMM fuses the final [64]x[64,1] dot) ----
    gemm_kernel<2, 16, 8, 2, 0, 1><<<gM625, 512, 0, stream>>>(x_mlp16, 4, g16, 4, wt_h1, head_b1, head_b1,
        hbn1_g, hbn1_b, h1, nullptr, nullptr, nullptr, nullptr, nullptr, nullptr, HID, 4, EP_BN_LRELU);
    gemm_kernel<1, 8, 8, 2, 0, 1><<<gM625, 512, 0, stream>>>(h1, 4, nullptr, 0, wt_h2, head_b2, head_b2,
        hbn2_g, hbn2_b, h2, nullptr, nullptr, nullptr, nullptr, nullptr, nullptr, HID / 2, 2, EP_BN_LRELU);
    gemm_kernel<1, 4, 4, 1, 1, 0><<<gM1250, 256, 0, stream>>>(h2, 2, nullptr, 0, wt_h3, head_b3, head_b3,
        nullptr, nullptr, nullptr, nullptr, nullptr, nullptr, head_w4, head_b4, out, HID / 4, 0, EP_LRELU);
}

// Round 13
// 460.584 us; speedup vs baseline: 1.0334x; 1.0334x over previous
//
#include <hip/hip_runtime.h>
#include <hip/hip_bf16.h>

#define N_NODES 20000
#define E_EDGES 320000
#define E_TOT   (E_EDGES + N_NODES)
#define IN_CH   128
#define HID     256
#define HEADS   8
#define CPH     32

enum { EP_BIAS = 0, EP_BN_LRELU = 1, EP_LRELU = 2 };

typedef _Float16 f16;
typedef f16  f16x2 __attribute__((ext_vector_type(2)));
typedef f16  f16x4 __attribute__((ext_vector_type(4)));
typedef f16  f16x8 __attribute__((ext_vector_type(8)));
typedef float f32x2 __attribute__((ext_vector_type(2)));
typedef float f32x4 __attribute__((ext_vector_type(4)));

__device__ __forceinline__ f16x2 h2max(f16x2 a, f16x2 b) {
#if __has_builtin(__builtin_elementwise_max)
    return __builtin_elementwise_max(a, b);
#else
    f16x2 r; r[0] = a[0] > b[0] ? a[0] : b[0]; r[1] = a[1] > b[1] ? a[1] : b[1]; return r;
#endif
}
__device__ __forceinline__ float hdot2(f16x2 a, f16x2 b, float c) {
#if __has_builtin(__builtin_amdgcn_fdot2)
    return __builtin_amdgcn_fdot2(a, b, c, false);
#else
    return c + (float)a[0] * (float)b[0] + (float)a[1] * (float)b[1];
#endif
}
__device__ __forceinline__ float fexp2(float x) {
#if __has_builtin(__builtin_amdgcn_exp2f)
    return __builtin_amdgcn_exp2f(x);
#else
    return exp2f(x);
#endif
}

// Fragment-major activation layout [rb][kb][ks][lane][8]: element (row, col):
//   rb=row>>4, m=row&15, kb=col>>6, ks=(col>>5)&1, q=(col>>3)&3, e=col&7, lane=(q<<4)|m
__device__ __forceinline__ size_t frag_idx(int row, int col, int KB) {
    int kb = col >> 6, ks = (col >> 5) & 1, q = (col >> 3) & 3, e = col & 7;
    return ((((size_t)(row >> 4) * KB + kb) * 2 + ks) << 9) + (((q << 4) | (row & 15)) << 3) + e;
}

// ---------------- weight prep: fp32 [K,Nc] -> fp16 fragment-major (B-operand) ----------------
struct WDesc { const float* src; f16* dst; int K; int Nc; int NTOT; int ct0; };
struct WDescs { WDesc d[14]; };

__global__ __launch_bounds__(256)
void wprep_kernel(WDescs ds) {
    WDesc w = ds.d[blockIdx.y];
    int total = w.K * w.Nc;
    int i = blockIdx.x * 256 + threadIdx.x;
    if (i < total) {
        int NT_local = w.Nc >> 4;
        int e  = i & 7;
        int l  = (i >> 3) & 63;
        int r  = i >> 9;
        int ct = r % NT_local;
        int q  = r / NT_local;
        int ks = q & 1;
        int kb = q >> 1;
        int n  = ct * 16 + (l & 15);
        int k  = kb * 64 + ks * 32 + ((l >> 4) << 3) + e;
        size_t di = (((size_t)(kb * 2 + ks) * w.NTOT + w.ct0 + ct) << 9) + (l << 3) + e;
        w.dst[di] = (f16)w.src[(size_t)k * w.Nc + n];
    }
}

// x fp32 row-major [N,128] -> f16 fragment-major (KB=2)
__global__ void cvt_frag_kernel(const float* __restrict__ in, f16* __restrict__ out) {
    int i = blockIdx.x * 256 + threadIdx.x;
    if (i < N_NODES * IN_CH) {
        int row = i / IN_CH, col = i - row * IN_CH;
        out[frag_idx(row, col, 2)] = (f16)in[i];
    }
}

// ---------------- barrier-free fp16 MFMA GEMM, frag-major A ----------------
template<int NT, int NTOT, int WAVES, int RT, int DOT, int OUTF>
__global__ __launch_bounds__(WAVES * 64)
void gemm_kernel(const f16* __restrict__ A1, int KB1,
                 const f16* __restrict__ A2, int KB2,
                 const f16* __restrict__ Wf,
                 const float* __restrict__ biasA,
                 const float* __restrict__ biasB,
                 const float* __restrict__ bng,
                 const float* __restrict__ bnb,
                 f16* __restrict__ out16A,
                 f16* __restrict__ out16B,
                 f16* __restrict__ dup16,
                 float* __restrict__ out32,
                 const float* __restrict__ dotw,
                 const float* __restrict__ dotb,
                 float* __restrict__ outdot,
                 int NcA, int KBo, int mode)
{
    __shared__ float red[DOT ? 16 : 1][DOT ? 65 : 1];
    const int tid  = threadIdx.x;
    const int wave = tid >> 6;
    const int lane = tid & 63;
    const int quad = lane >> 4;
    const int rb0 = blockIdx.x * RT;
    const int KBt = KB1 + KB2;

    f32x4 acc[RT][NT];
#pragma unroll
    for (int t = 0; t < RT; ++t)
#pragma unroll
        for (int j = 0; j < NT; ++j) acc[t][j] = (f32x4){0.f, 0.f, 0.f, 0.f};

#pragma unroll 2
    for (int kb = 0; kb < KBt; ++kb) {
#pragma unroll
        for (int ks = 0; ks < 2; ++ks) {
            f16x8 a[RT];
#pragma unroll
            for (int t = 0; t < RT; ++t) {
                const f16* ap = (kb < KB1)
                    ? A1 + (((((size_t)(rb0 + t)) * KB1 + kb) * 2 + ks) << 9) + (lane << 3)
                    : A2 + (((((size_t)(rb0 + t)) * KB2 + (kb - KB1)) * 2 + ks) << 9) + (lane << 3);
                a[t] = *(const f16x8*)ap;      // 64 x 16 B contiguous: one coalesced load
            }
            const f16* bp = Wf + (((size_t)(kb * 2 + ks) * NTOT + wave * NT) << 9) + (lane << 3);
#pragma unroll
            for (int ct = 0; ct < NT; ++ct) {
                f16x8 b = *(const f16x8*)(bp + ((size_t)ct << 9));
#pragma unroll
                for (int t = 0; t < RT; ++t)
                    acc[t][ct] = __builtin_amdgcn_mfma_f32_16x16x32_f16(a[t], b, acc[t][ct], 0, 0, 0);
            }
        }
    }

    // epilogue: C/D layout col=lane&15, row=quad*4+reg
    const int c0 = lane & 15;
    const int NcB = NTOT * 16 - NcA;
#pragma unroll
    for (int t = 0; t < RT; ++t) {
        const int r0 = (rb0 + t) * 16 + (quad << 2);
#pragma unroll
        for (int ct = 0; ct < NT; ++ct) {
            int col = (wave * NT + ct) * 16 + c0;
            bool isB = col >= NcA;
            int colL = isB ? col - NcA : col;
            float bv = isB ? biasB[colL] : biasA[colL];
            float sc = 1.f, sh = 0.f;
            if (mode == EP_BN_LRELU) {
                sc = bng[col] * rsqrtf(1.f + 1e-5f);
                sh = bnb[col];
            }
#pragma unroll
            for (int reg = 0; reg < 4; ++reg) {
                int row = r0 + reg;
                float v = acc[t][ct][reg] + bv;
                if (mode == EP_BN_LRELU) { v = v * sc + sh; v = v > 0.f ? v : 0.1f * v; }
                else if (mode == EP_LRELU) { v = v > 0.f ? v : 0.1f * v; }
                if (DOT) {
                    red[(quad << 2) + reg][col] = v * dotw[col];
                } else if (OUTF) {
                    size_t idx = frag_idx(row, col, KBo);
                    out16A[idx] = (f16)v;
                    if (dup16) dup16[idx] = (f16)v;
                    if (out32) out32[(size_t)row * NcA + col] = v;
                } else {
                    f16* Cout = isB ? out16B : out16A;
                    int stride = isB ? NcB : NcA;
                    Cout[(size_t)row * stride + colL] = (f16)v;
                }
            }
        }
    }

    if (DOT) {   // RT==1, NTOT*16 == 64
        __syncthreads();
        if (wave == 0) {
            int r = lane & 15, q = lane >> 4;
            float psum = 0.f;
#pragma unroll
            for (int j = 0; j < 16; ++j) psum += red[r][q * 16 + j];
            psum += __shfl_xor(psum, 16, 64);
            psum += __shfl_xor(psum, 32, 64);
            if (lane < 16) outdot[rb0 * 16 + r] = psum + dotb[0];
        }
    }
}

// ---------------- CSR build ----------------
__global__ void deg_count_kernel(const int* __restrict__ dst, int* __restrict__ cnt) {
    int e = blockIdx.x * 256 + threadIdx.x;
    if (e < E_EDGES) atomicAdd(&cnt[dst[e]], 1);
}
__global__ __launch_bounds__(1024)
void scan_kernel(const int* __restrict__ cnt, int* __restrict__ off) {
    __shared__ int wsum[16];
    __shared__ int wpre[16];
    __shared__ int tot_s;
    __shared__ int carry_s;
    const int tid = threadIdx.x, wv = tid >> 6, ln = tid & 63;
    if (tid == 0) carry_s = 0;
    __syncthreads();
    for (int base = 0; base < N_NODES; base += 1024) {
        int i = base + tid;
        int v = (i < N_NODES) ? cnt[i] + 1 : 0;   // +1 = self loop
        int s = v;
#pragma unroll
        for (int d = 1; d < 64; d <<= 1) { int t = __shfl_up(s, d, 64); if (ln >= d) s += t; }
        if (ln == 63) wsum[wv] = s;
        __syncthreads();
        if (tid < 16) {
            int t = wsum[tid];
            int sc = t;
#pragma unroll
            for (int d = 1; d < 16; d <<= 1) { int u = __shfl_up(sc, d, 16); if (tid >= d) sc += u; }
            wpre[tid] = sc - t;
            if (tid == 15) tot_s = sc;
        }
        __syncthreads();
        if (i < N_NODES) off[i] = carry_s + wpre[wv] + s - v;
        __syncthreads();
        if (tid == 0) carry_s += tot_s;
        __syncthreads();
    }
    if (threadIdx.x == 0) off[N_NODES] = carry_s;
}
__global__ void fill_kernel(const int* __restrict__ src, const int* __restrict__ dst,
                            const int* __restrict__ off, int* __restrict__ cur, int* __restrict__ csr) {
    int i = blockIdx.x * 256 + threadIdx.x;
    if (i < E_EDGES) {
        int d = dst[i];
        int pos = atomicAdd(&cur[d], 1);
        csr[off[d] + pos] = src[i];
    } else {
        int j = i - E_EDGES;
        if (j < N_NODES) csr[off[j + 1] - 1] = j;
    }
}

// ---------------- fused GATv2 aggregation: 1 wave/node, 4 ch/thread ----------------
__global__ __launch_bounds__(256)
void gat_agg_kernel(const f16* __restrict__ xl, const f16* __restrict__ xr,
                    float* __restrict__ g, f16* __restrict__ g16,
                    const int* __restrict__ off, const int* __restrict__ csr,
                    const float* __restrict__ att,
                    const float* __restrict__ bias,
                    const float* __restrict__ lng,
                    const float* __restrict__ lnb)
{
    const int wv = threadIdx.x >> 6;
    const int ln = threadIdx.x & 63;           // channels 4ln..4ln+3; head = ln>>3
    const int n  = blockIdx.x * 4 + wv;
    if (n >= N_NODES) return;

    const f16x4* xl4 = (const f16x4*)xl;
    f16x4 xrv = ((const f16x4*)xr)[n * 64 + ln];
    f16x2 xr01; xr01[0] = xrv[0]; xr01[1] = xrv[1];
    f16x2 xr23; xr23[0] = xrv[2]; xr23[1] = xrv[3];
    float4 avf = ((const float4*)att)[ln];
    const float L2E = 1.44269504f;             // exp(x) = exp2(x*log2e)
    f16x2 av01; av01[0] = (f16)(avf.x * L2E); av01[1] = (f16)(avf.y * L2E);
    f16x2 av23; av23[0] = (f16)(avf.z * L2E); av23[1] = (f16)(avf.w * L2E);
    const f16x2 k02 = { (f16)0.2f, (f16)0.2f };

    float s = 0.f, o0 = 0.f, o1 = 0.f, o2 = 0.f, o3 = 0.f;

    auto proc = [&](f16x4 xv) {
        f16x2 x01; x01[0] = xv[0]; x01[1] = xv[1];
        f16x2 x23; x23[0] = xv[2]; x23[1] = xv[3];
        f16x2 v01 = x01 + xr01;
        f16x2 v23 = x23 + xr23;
        f16x2 l01 = h2max(v01, v01 * k02);     // leaky 0.2 (packed)
        f16x2 l23 = h2max(v23, v23 * k02);
        float pr = hdot2(l01, av01, hdot2(l23, av23, 0.f));
        pr += __shfl_xor(pr, 4, 8);
        pr += __shfl_xor(pr, 2, 8);
        pr += __shfl_xor(pr, 1, 8);            // per-head logit (8 lanes = 32 ch)
        float e = fexp2(pr);                    // logits bounded: no running max needed
        s += e;
        // mixed-precision FMA: encourage v_fma_mix_f32 (f16 src, f32 acc)
        o0 = fmaf((float)xv[0], e, o0);
        o1 = fmaf((float)xv[1], e, o1);
        o2 = fmaf((float)xv[2], e, o2);
        o3 = fmaf((float)xv[3], e, o3);
    };

    int p = off[n], end = off[n + 1];
    for (; p + 4 <= end; p += 4) {
        int s0 = csr[p], s1 = csr[p + 1], s2 = csr[p + 2], s3 = csr[p + 3];
        f16x4 r0 = xl4[s0 * 64 + ln];          // int32 offsets: 32-bit addressing
        f16x4 r1 = xl4[s1 * 64 + ln];
        f16x4 r2 = xl4[s2 * 64 + ln];
        f16x4 r3 = xl4[s3 * 64 + ln];
        proc(r0); proc(r1); proc(r2); proc(r3);
    }
    for (; p < end; ++p) {
        f16x4 r0 = xl4[csr[p] * 64 + ln];
        proc(r0);
    }

    float inv = 1.f / (s + 1e-16f);
    float4 bi = ((const float4*)bias)[ln];
    float y0 = o0 * inv + bi.x;
    float y1 = o1 * inv + bi.y;
    float y2 = o2 * inv + bi.z;
    float y3 = o3 * inv + bi.w;

    // LayerNorm over 256 channels, pure wave-shuffle
    float s1 = y0 + y1 + y2 + y3;
    float s2 = y0 * y0 + y1 * y1 + y2 * y2 + y3 * y3;
#pragma unroll
    for (int d = 32; d; d >>= 1) { s1 += __shfl_xor(s1, d, 64); s2 += __shfl_xor(s2, d, 64); }
    float mu  = s1 * (1.f / HID);
    float ex2 = s2 * (1.f / HID);
    float rstd = rsqrtf(ex2 - mu * mu + 1e-5f);
    float4 lg = ((const float4*)lng)[ln];
    float4 lb = ((const float4*)lnb)[ln];
    float nv0 = (y0 - mu) * rstd * lg.x + lb.x; nv0 = nv0 > 0.f ? nv0 : 0.1f * nv0;
    float nv1 = (y1 - mu) * rstd * lg.y + lb.y; nv1 = nv1 > 0.f ? nv1 : 0.1f * nv1;
    float nv2 = (y2 - mu) * rstd * lg.z + lb.z; nv2 = nv2 > 0.f ? nv2 : 0.1f * nv2;
    float nv3 = (y3 - mu) * rstd * lg.w + lb.w; nv3 = nv3 > 0.f ? nv3 : 0.1f * nv3;

    float4 gv = ((const float4*)g)[n * 64 + ln];
    float g0 = nv0 + gv.x, g1 = nv1 + gv.y, g2 = nv2 + gv.z, g3 = nv3 + gv.w;
    ((float4*)g)[n * 64 + ln] = make_float4(g0, g1, g2, g3);
    // g16 mirror in fragment-major layout (KB=4)
    f16x4 gh; gh[0] = (f16)g0; gh[1] = (f16)g1; gh[2] = (f16)g2; gh[3] = (f16)g3;
    *(f16x4*)&g16[frag_idx(n, 4 * ln, 4)] = gh;
}

static inline size_t align_up(size_t v, size_t a) { return (v + a - 1) & ~(a - 1); }

extern "C" void kernel_launch(void* const* d_in, const int* in_sizes, int n_in,
                              void* d_out, int out_size, void* d_ws, size_t ws_size,
                              hipStream_t stream)
{
    const float* x      = (const float*)d_in[0];
    const int*   ei     = (const int*)d_in[1];
    const float* mlp_w1 = (const float*)d_in[2];
    const float* mlp_b1 = (const float*)d_in[3];
    const float* bn1_g  = (const float*)d_in[4];
    const float* bn1_b  = (const float*)d_in[5];
    const float* mlp_w2 = (const float*)d_in[6];
    const float* mlp_b2 = (const float*)d_in[7];
    const float* bn2_g  = (const float*)d_in[8];
    const float* bn2_b  = (const float*)d_in[9];
    const float* mlp_w3 = (const float*)d_in[10];
    const float* mlp_b3 = (const float*)d_in[11];
    const float* gat_wl = (const float*)d_in[12];
    const float* gat_bl = (const float*)d_in[13];
    const float* gat_wr = (const float*)d_in[14];
    const float* gat_br = (const float*)d_in[15];
    const float* gat_att  = (const float*)d_in[16];
    const float* gat_bias = (const float*)d_in[17];
    const float* ln_g   = (const float*)d_in[18];
    const float* ln_b   = (const float*)d_in[19];
    const float* head_w1 = (const float*)d_in[20];
    const float* head_b1 = (const float*)d_in[21];
    const float* hbn1_g  = (const float*)d_in[22];
    const float* hbn1_b  = (const float*)d_in[23];
    const float* head_w2 = (const float*)d_in[24];
    const float* head_b2 = (const float*)d_in[25];
    const float* hbn2_g  = (const float*)d_in[26];
    const float* hbn2_b  = (const float*)d_in[27];
    const float* head_w3 = (const float*)d_in[28];
    const float* head_b3 = (const float*)d_in[29];
    const float* head_w4 = (const float*)d_in[30];
    const float* head_b4 = (const float*)d_in[31];
    float* out = (float*)d_out;

    // ---- workspace layout ----
    char* w = (char*)d_ws;
    size_t p = 0;
    int* off  = (int*)(w + p); p = align_up(p + (N_NODES + 1) * sizeof(int), 64);
    int* fill = (int*)(w + p); p = align_up(p + N_NODES * sizeof(int), 64);
    int* cur  = (int*)(w + p); p = align_up(p + N_NODES * sizeof(int), 64);
    int* csr  = (int*)(w + p); p = align_up(p + E_TOT * sizeof(int), 64);
    float* g32 = (float*)(w + p); p = align_up(p + (size_t)N_NODES * HID * 4, 64);
    auto halloc = [&](size_t elems) {
        f16* q = (f16*)(w + p);
        p = align_up(p + elems * 2, 1024);
        return q;
    };
    f16* x16     = halloc((size_t)N_NODES * IN_CH);   // frag KB=2
    f16* h1      = halloc((size_t)N_NODES * HID);     // frag KB=4
    f16* h2      = halloc((size_t)N_NODES * HID);     // frag KB=4 / KB=2 for head2
    f16* x_mlp16 = halloc((size_t)N_NODES * HID);     // frag KB=4
    f16* g16     = halloc((size_t)N_NODES * HID);     // frag KB=4
    f16* xl16    = halloc((size_t)N_NODES * HID);     // row-major (agg input)
    f16* xr16    = halloc((size_t)N_NODES * HID);     // row-major (agg input)
    f16* wt_mlp1 = halloc((size_t)IN_CH * HID);
    f16* wt_mlp2 = halloc((size_t)HID * HID);
    f16* wt_mlp3 = halloc((size_t)HID * HID);
    f16* wt_g[4];
    for (int i = 0; i < 4; ++i) wt_g[i] = halloc((size_t)HID * 2 * HID);
    f16* wt_h1 = halloc((size_t)2 * HID * HID);
    f16* wt_h2 = halloc((size_t)HID * (HID / 2));
    f16* wt_h3 = halloc((size_t)(HID / 2) * (HID / 4));
    (void)ws_size; (void)in_sizes; (void)n_in; (void)out_size;

    const int* e_src = ei;
    const int* e_dst = ei + E_EDGES;

    dim3 blk(256);
    dim3 gM625((N_NODES + 31) / 32);   // RT=2: 625 exact
    dim3 gM1250((N_NODES + 15) / 16);  // RT=1: 1250 exact

    // ---- weight prep (fp32 -> fp16 fragment-major; wl+wr fused per layer) ----
    WDescs ds;
    ds.d[0]  = { mlp_w1, wt_mlp1, IN_CH, HID, 16, 0 };
    ds.d[1]  = { mlp_w2, wt_mlp2, HID, HID, 16, 0 };
    ds.d[2]  = { mlp_w3, wt_mlp3, HID, HID, 16, 0 };
    for (int i = 0; i < 4; ++i) {
        ds.d[3 + 2 * i] = { gat_wl + (size_t)i * HID * HID, wt_g[i], HID, HID, 32, 0 };
        ds.d[4 + 2 * i] = { gat_wr + (size_t)i * HID * HID, wt_g[i], HID, HID, 32, 16 };
    }
    ds.d[11] = { head_w1, wt_h1, 2 * HID, HID, 16, 0 };
    ds.d[12] = { head_w2, wt_h2, HID, HID / 2, 8, 0 };
    ds.d[13] = { head_w3, wt_h3, HID / 2, HID / 4, 4, 0 };
    {
        dim3 gp((2 * HID * HID + 255) / 256, 14);
        wprep_kernel<<<gp, blk, 0, stream>>>(ds);
    }
    cvt_frag_kernel<<<(N_NODES * IN_CH + 255) / 256, blk, 0, stream>>>(x, x16);

    // ---- CSR by destination ----
    hipMemsetAsync(fill, 0, (size_t)((char*)cur - (char*)fill) + N_NODES * sizeof(int), stream);
    deg_count_kernel<<<(E_EDGES + 255) / 256, blk, 0, stream>>>(e_dst, fill);
    scan_kernel<<<1, 1024, 0, stream>>>(fill, off);
    fill_kernel<<<(E_TOT + 255) / 256, blk, 0, stream>>>(e_src, e_dst, off, cur, csr);

    // ---- MLP stem (frag-major f16 I/O; MLP3 also emits g16 frag + g32 row-major) ----
    gemm_kernel<2, 16, 8, 2, 0, 1><<<gM625, 512, 0, stream>>>(x16, 2, nullptr, 0, wt_mlp1, mlp_b1, mlp_b1,
        bn1_g, bn1_b, h1, nullptr, nullptr, nullptr, nullptr, nullptr, nullptr, HID, 4, EP_BN_LRELU);
    gemm_kernel<2, 16, 8, 2, 0, 1><<<gM625, 512, 0, stream>>>(h1, 4, nullptr, 0, wt_mlp2, mlp_b2, mlp_b2,
        bn2_g, bn2_b, h2, nullptr, nullptr, nullptr, nullptr, nullptr, nullptr, HID, 4, EP_BN_LRELU);
    gemm_kernel<2, 16, 8, 2, 0, 1><<<gM625, 512, 0, stream>>>(h2, 4, nullptr, 0, wt_mlp3, mlp_b3, mlp_b3,
        nullptr, nullptr, x_mlp16, nullptr, g16, g32, nullptr, nullptr, nullptr, HID, 4, EP_BIAS);

    // ---- GAT layers (fused wl|wr dual-output GEMM + fused aggregation) ----
    for (int i = 0; i < 4; ++i) {
        gemm_kernel<4, 32, 8, 2, 0, 0><<<gM625, 512, 0, stream>>>(g16, 4, nullptr, 0, wt_g[i],
            gat_bl + i * HID, gat_br + i * HID, nullptr, nullptr,
            xl16, xr16, nullptr, nullptr, nullptr, nullptr, nullptr, HID, 0, EP_BIAS);
        gat_agg_kernel<<<(N_NODES + 3) / 4, blk, 0, stream>>>(xl16, xr16, g32, g16, off, csr,
                                                              gat_att + i * HID, gat_bias + i * HID,
                                                              ln_g + i * HID, ln_b + i * HID);
    }

    // ---- regression head (head3 GEMM fuses the final [64]x[64,1] dot) ----
    gemm_kernel<2, 16, 8, 2, 0, 1><<<gM625, 512, 0, stream>>>(x_mlp16, 4, g16, 4, wt_h1, head_b1, head_b1,
        hbn1_g, hbn1_b, h1, nullptr, nullptr, nullptr, nullptr, nullptr, nullptr, HID, 4, EP_BN_LRELU);
    gemm_kernel<1, 8, 8, 2, 0, 1><<<gM625, 512, 0, stream>>>(h1, 4, nullptr, 0, wt_h2, head_b2, head_b2,
        hbn2_g, hbn2_b, h2, nullptr, nullptr, nullptr, nullptr, nullptr, nullptr, HID / 2, 2, EP_BN_LRELU);
    gemm_kernel<1, 4, 4, 1, 1, 0><<<gM1250, 256, 0, stream>>>(h2, 2, nullptr, 0, wt_h3, head_b3, head_b3,
        nullptr, nullptr, nullptr, nullptr, nullptr, nullptr, head_w4, head_b4, out, HID / 4, 0, EP_LRELU);
}